// Round 6
// baseline (210.686 us; speedup 1.0000x reference)
//
#include <hip/hip_runtime.h>

using u16 = unsigned short;
typedef __attribute__((ext_vector_type(8))) short short8;
typedef __attribute__((ext_vector_type(4))) float floatx4;

#define NQ 1024
#define NK 2048
#define DD 512

__device__ __forceinline__ float bf2f(u16 u) {
  union { unsigned u; float f; } x; x.u = ((unsigned)u) << 16; return x.f;
}
// packed RTNE f32x2 -> bf16x2 (bits[15:0]=lo, [31:16]=hi)
__device__ __forceinline__ unsigned cvt_pk_bf16(float lo, float hi) {
  unsigned r;
  asm("v_cvt_pk_bf16_f32 %0, %1, %2" : "=v"(r) : "v"(lo), "v"(hi));
  return r;
}
__device__ __forceinline__ float wave_sum(float v) {
#pragma unroll
  for (int off = 32; off > 0; off >>= 1) v += __shfl_down(v, off, 64);
  return v;
}
__device__ __forceinline__ void gload16(const u16* g, const u16* l) {
  __builtin_amdgcn_global_load_lds(
      (const __attribute__((address_space(1))) void*)g,
      (__attribute__((address_space(3))) void*)l, 16, 0, 0);
}

// ---- fused: wave-per-row LN (inputs+context) + weight cvt + zero Z/colV ----
// Wq/bq are pre-scaled by qsc = 512^-0.5 * log2(e) so QK epilogue is exp2(acc).
__global__ __launch_bounds__(256) void ln_prep(
    const float* __restrict__ X1, const float* __restrict__ G1,
    const float* __restrict__ B1, u16* __restrict__ Y1,
    const float* __restrict__ X2, const float* __restrict__ G2,
    const float* __restrict__ B2, u16* __restrict__ Y2,
    const float* __restrict__ Wq, const float* __restrict__ Wk,
    const float* __restrict__ Wv, u16* __restrict__ wqb,
    u16* __restrict__ wkb, u16* __restrict__ wvb, float* __restrict__ Zero,
    float qsc) {
  const int bx = blockIdx.x;
  const int t = threadIdx.x;
  if (bx >= 6144) {
    int e = bx - 6144;
    if (e < 768) {
      const float* src = e < 256 ? Wq : (e < 512 ? Wk : Wv);
      u16* dst = e < 256 ? wqb : (e < 512 ? wkb : wvb);
      const float ws = e < 256 ? qsc : 1.f;
      int i = ((e & 255) * 256 + t) * 4;
      float4 v = *(const float4*)(src + i);
      union { unsigned u[2]; ushort4 s; } ou;
      ou.u[0] = cvt_pk_bf16(v.x * ws, v.y * ws);
      ou.u[1] = cvt_pk_bf16(v.z * ws, v.w * ws);
      *(ushort4*)(dst + i) = ou.s;
    } else {
      int i = ((e - 768) * 256 + t) * 4;
      float4 z = {0.f, 0.f, 0.f, 0.f};
      *(float4*)(Zero + i) = z;
    }
    return;
  }
  const int wave = t >> 6, lane = t & 63;
  int row = bx * 4 + wave;
  const float *X, *G, *Bv; u16* Y;
  if (row < 8192) { X = X1; G = G1; Bv = B1; Y = Y1; }
  else { row -= 8192; X = X2; G = G2; Bv = B2; Y = Y2; }
  const float4* Xp = (const float4*)(X + (long)row * DD);
  float4 v0 = Xp[lane * 2], v1 = Xp[lane * 2 + 1];
  float s = v0.x + v0.y + v0.z + v0.w + v1.x + v1.y + v1.z + v1.w;
  float ss = v0.x * v0.x + v0.y * v0.y + v0.z * v0.z + v0.w * v0.w +
             v1.x * v1.x + v1.y * v1.y + v1.z * v1.z + v1.w * v1.w;
  s = wave_sum(s);  s = __shfl(s, 0, 64);
  ss = wave_sum(ss); ss = __shfl(ss, 0, 64);
  float mu = s * (1.f / DD);
  float var = ss * (1.f / DD) - mu * mu;
  float rs = rsqrtf(var + 1e-5f);
  const float4* Gp = (const float4*)G;
  const float4* Bp = (const float4*)Bv;
  float4 g0 = Gp[lane * 2], g1 = Gp[lane * 2 + 1];
  float4 b0 = Bp[lane * 2], b1 = Bp[lane * 2 + 1];
  union { unsigned u[4]; short8 s8; } ou;
  ou.u[0] = cvt_pk_bf16((v0.x - mu) * rs * g0.x + b0.x,
                        (v0.y - mu) * rs * g0.y + b0.y);
  ou.u[1] = cvt_pk_bf16((v0.z - mu) * rs * g0.z + b0.z,
                        (v0.w - mu) * rs * g0.w + b0.w);
  ou.u[2] = cvt_pk_bf16((v1.x - mu) * rs * g1.x + b1.x,
                        (v1.y - mu) * rs * g1.y + b1.y);
  ou.u[3] = cvt_pk_bf16((v1.z - mu) * rs * g1.z + b1.z,
                        (v1.w - mu) * rs * g1.w + b1.w);
  *(short8*)(Y + (long)row * DD + lane * 8) = ou.s8;
}

// ---------- q-proj + k-proj (B^T GEMM, K=512, BK=64, swizzled LDS) ----------
__global__ __launch_bounds__(256) void gemm_proj(
    const u16* __restrict__ A1, const u16* __restrict__ W1,
    const float* __restrict__ b1, u16* __restrict__ C1,
    const u16* __restrict__ A2, const u16* __restrict__ W2,
    const float* __restrict__ b2, u16* __restrict__ C2,
    float bsc1, float bsc2) {
  __shared__ u16 smem[16384];   // lA | lB in K-loop; 128x128 C-tile in epilogue
  u16* lA = smem;
  u16* lB = smem + 8192;
  const u16 *A, *B; const float* bias; u16* Cout; float bsc;
  int m0 = blockIdx.x * 128;
  if (blockIdx.x < 64) { A = A1; B = W1; bias = b1; Cout = C1; bsc = bsc1; }
  else { A = A2; B = W2; bias = b2; Cout = C2; bsc = bsc2;
         m0 = (blockIdx.x - 64) * 128; }
  const int n0 = blockIdx.y * 128;
  const int t = threadIdx.x, wave = t >> 6, lane = t & 63;
  const int fm = lane & 15, fq = lane >> 4;
  const int wm = (wave >> 1) * 64, wn = (wave & 1) * 64;

  const int srow = t >> 3;
  const int swz = ((t & 7) ^ (srow & 7)) * 8;
  const u16* gA = A + (long)(m0 + srow) * 512 + swz;
  const u16* gB = B + (long)(n0 + srow) * 512 + swz;
  u16* dA = lA + wave * 512;
  u16* dB = lB + wave * 512;

  floatx4 acc[4][4];
#pragma unroll
  for (int x = 0; x < 4; ++x)
#pragma unroll
    for (int y = 0; y < 4; ++y) { floatx4 z = {0.f, 0.f, 0.f, 0.f}; acc[x][y] = z; }

#pragma unroll 1
  for (int kt = 0; kt < 8; ++kt) {
    gload16(gA, dA);
    gload16(gA + 32L * 512, dA + 2048);
    gload16(gA + 64L * 512, dA + 4096);
    gload16(gA + 96L * 512, dA + 6144);
    gload16(gB, dB);
    gload16(gB + 32L * 512, dB + 2048);
    gload16(gB + 64L * 512, dB + 4096);
    gload16(gB + 96L * 512, dB + 6144);
    gA += 64; gB += 64;
    __syncthreads();
#pragma unroll
    for (int ks = 0; ks < 2; ++ks) {
      short8 af[4], bfr[4];
      const int csl = ((ks * 4 + fq) ^ (fm & 7)) * 8;
#pragma unroll
      for (int x = 0; x < 4; ++x)
        af[x] = *(const short8*)&lA[(wm + x * 16 + fm) * 64 + csl];
#pragma unroll
      for (int y = 0; y < 4; ++y)
        bfr[y] = *(const short8*)&lB[(wn + y * 16 + fm) * 64 + csl];
#pragma unroll
      for (int x = 0; x < 4; ++x)
#pragma unroll
        for (int y = 0; y < 4; ++y)
          acc[x][y] = __builtin_amdgcn_mfma_f32_16x16x32_bf16(af[x], bfr[y], acc[x][y], 0, 0, 0);
    }
    __syncthreads();
  }

  float bs[4];
  int cs[4];
#pragma unroll
  for (int y = 0; y < 4; ++y) {
    bs[y] = bias[n0 + wn + y * 16 + fm] * bsc;
    cs[y] = ((((wn >> 4) + y) ^ fq) * 16) + fm;
  }
#pragma unroll
  for (int x = 0; x < 4; ++x)
#pragma unroll
    for (int r = 0; r < 4; ++r) {
      int rowl = wm + x * 16 + fq * 4 + r;
      unsigned p01 = cvt_pk_bf16(acc[x][0][r] + bs[0], acc[x][1][r] + bs[1]);
      unsigned p23 = cvt_pk_bf16(acc[x][2][r] + bs[2], acc[x][3][r] + bs[3]);
      smem[rowl * 128 + cs[0]] = (u16)p01;
      smem[rowl * 128 + cs[1]] = (u16)(p01 >> 16);
      smem[rowl * 128 + cs[2]] = (u16)p23;
      smem[rowl * 128 + cs[3]] = (u16)(p23 >> 16);
    }
  __syncthreads();
#pragma unroll
  for (int p = 0; p < 8; ++p) {
    int rowl = p * 16 + (t >> 4);
    int c = t & 15;
    int q = (rowl >> 2) & 3;
    short8 v = *(const short8*)&smem[rowl * 128 + (((c >> 1) ^ q) * 16) + (c & 1) * 8];
    *(short8*)(Cout + (long)(m0 + rowl) * 512 + n0 + c * 8) = v;
  }
}

// ------- merged: QK (blocks 0..1023) + v-projT unscaled (1024..1535) --------
// qb is pre-scaled so E = exp2(acc) directly.
__global__ __launch_bounds__(256) void qk_vproj(
    const u16* __restrict__ qb, const u16* __restrict__ kb,
    u16* __restrict__ E, float* __restrict__ Z,
    const u16* __restrict__ wvb, const u16* __restrict__ cb,
    const float* __restrict__ bv, u16* __restrict__ vT,
    float* __restrict__ colV) {
  __shared__ u16 smem[16384];
  __shared__ float colred[128];
  u16* lA = smem;
  u16* lB = smem + 8192;

  const int bx = blockIdx.x;
  const bool is_qk = bx < 1024;
  const u16 *A, *B;
  int m0, n0, b;
  if (is_qk) {
    b = bx & 7;
    n0 = ((bx >> 3) & 15) * 128;
    m0 = (bx >> 7) * 128;
    A = qb + (long)b * (1024L * 512);
    B = kb + (long)b * (2048L * 512);
  } else {
    int e = bx - 1024;
    m0 = (e & 3) * 128;
    n0 = (e >> 2) * 128;
    b = 0;
    A = wvb;
    B = cb;
  }
  const int t = threadIdx.x, wave = t >> 6, lane = t & 63;
  const int fm = lane & 15, fq = lane >> 4;
  const int wm = (wave >> 1) * 64, wn = (wave & 1) * 64;

  const int srow = t >> 3;
  const int swz = ((t & 7) ^ (srow & 7)) * 8;
  const u16* gA = A + (long)(m0 + srow) * 512 + swz;
  const u16* gB = B + (long)(n0 + srow) * 512 + swz;
  u16* dA = lA + wave * 512;
  u16* dB = lB + wave * 512;

  floatx4 acc[4][4];
#pragma unroll
  for (int x = 0; x < 4; ++x)
#pragma unroll
    for (int y = 0; y < 4; ++y) { floatx4 z = {0.f, 0.f, 0.f, 0.f}; acc[x][y] = z; }

#pragma unroll 1
  for (int kt = 0; kt < 8; ++kt) {
    gload16(gA, dA);
    gload16(gA + 32L * 512, dA + 2048);
    gload16(gA + 64L * 512, dA + 4096);
    gload16(gA + 96L * 512, dA + 6144);
    gload16(gB, dB);
    gload16(gB + 32L * 512, dB + 2048);
    gload16(gB + 64L * 512, dB + 4096);
    gload16(gB + 96L * 512, dB + 6144);
    gA += 64; gB += 64;
    __syncthreads();
#pragma unroll
    for (int ks = 0; ks < 2; ++ks) {
      short8 af[4], bfr[4];
      const int csl = ((ks * 4 + fq) ^ (fm & 7)) * 8;
#pragma unroll
      for (int x = 0; x < 4; ++x)
        af[x] = *(const short8*)&lA[(wm + x * 16 + fm) * 64 + csl];
#pragma unroll
      for (int y = 0; y < 4; ++y)
        bfr[y] = *(const short8*)&lB[(wn + y * 16 + fm) * 64 + csl];
#pragma unroll
      for (int x = 0; x < 4; ++x)
#pragma unroll
        for (int y = 0; y < 4; ++y)
          acc[x][y] = __builtin_amdgcn_mfma_f32_16x16x32_bf16(af[x], bfr[y], acc[x][y], 0, 0, 0);
    }
    __syncthreads();
  }

  int cs[4];
#pragma unroll
  for (int y = 0; y < 4; ++y) cs[y] = ((((wn >> 4) + y) ^ fq) * 16) + fm;

  if (is_qk) {
    float s4[4] = {0.f, 0.f, 0.f, 0.f};
#pragma unroll
    for (int x = 0; x < 4; ++x)
#pragma unroll
      for (int r = 0; r < 4; ++r) {
        int rowl = wm + x * 16 + fq * 4 + r;
        float e0 = __builtin_amdgcn_exp2f(acc[x][0][r]);
        float e1 = __builtin_amdgcn_exp2f(acc[x][1][r]);
        float e2 = __builtin_amdgcn_exp2f(acc[x][2][r]);
        float e3 = __builtin_amdgcn_exp2f(acc[x][3][r]);
        s4[0] += e0; s4[1] += e1; s4[2] += e2; s4[3] += e3;
        unsigned p01 = cvt_pk_bf16(e0, e1);
        unsigned p23 = cvt_pk_bf16(e2, e3);
        smem[rowl * 128 + cs[0]] = (u16)p01;
        smem[rowl * 128 + cs[1]] = (u16)(p01 >> 16);
        smem[rowl * 128 + cs[2]] = (u16)p23;
        smem[rowl * 128 + cs[3]] = (u16)(p23 >> 16);
      }
#pragma unroll
    for (int y = 0; y < 4; ++y) {
      s4[y] += __shfl_xor(s4[y], 16, 64);
      s4[y] += __shfl_xor(s4[y], 32, 64);
    }
    if (t < 128) colred[t] = 0.f;
    __syncthreads();
    u16* Eg = E + (long)b * (1024L * 2048);
#pragma unroll
    for (int p = 0; p < 8; ++p) {
      int rowl = p * 16 + (t >> 4);
      int c = t & 15;
      int q = (rowl >> 2) & 3;
      short8 v = *(const short8*)&smem[rowl * 128 + (((c >> 1) ^ q) * 16) + (c & 1) * 8];
      *(short8*)(Eg + (long)(m0 + rowl) * 2048 + n0 + c * 8) = v;
    }
    if (fq == 0) {
#pragma unroll
      for (int y = 0; y < 4; ++y) atomicAdd(&colred[wn + y * 16 + fm], s4[y]);
    }
    __syncthreads();
    if (t < 128) atomicAdd(&Z[b * 2048 + n0 + t], colred[t]);
  } else {
    const int bb = n0 >> 11;
    const int j0c = n0 & 2047;
    float bsr[4][4];
#pragma unroll
    for (int x = 0; x < 4; ++x)
#pragma unroll
      for (int r = 0; r < 4; ++r)
        bsr[x][r] = bv[m0 + wm + x * 16 + fq * 4 + r];
    float rs[4][4];
#pragma unroll
    for (int x = 0; x < 4; ++x)
#pragma unroll
      for (int r = 0; r < 4; ++r) rs[x][r] = 0.f;
#pragma unroll
    for (int x = 0; x < 4; ++x)
#pragma unroll
      for (int r = 0; r < 4; ++r) {
        int rowl = wm + x * 16 + fq * 4 + r;
        float v0 = acc[x][0][r] + bsr[x][r];
        float v1 = acc[x][1][r] + bsr[x][r];
        float v2 = acc[x][2][r] + bsr[x][r];
        float v3 = acc[x][3][r] + bsr[x][r];
        rs[x][r] += v0 + v1 + v2 + v3;
        unsigned p01 = cvt_pk_bf16(v0, v1);
        unsigned p23 = cvt_pk_bf16(v2, v3);
        smem[rowl * 128 + cs[0]] = (u16)p01;
        smem[rowl * 128 + cs[1]] = (u16)(p01 >> 16);
        smem[rowl * 128 + cs[2]] = (u16)p23;
        smem[rowl * 128 + cs[3]] = (u16)(p23 >> 16);
      }
    __syncthreads();
    u16* Cg = vT + (long)bb * (512L * 2048) + j0c;
#pragma unroll
    for (int p = 0; p < 8; ++p) {
      int rowl = p * 16 + (t >> 4);
      int c = t & 15;
      int q = (rowl >> 2) & 3;
      short8 v = *(const short8*)&smem[rowl * 128 + (((c >> 1) ^ q) * 16) + (c & 1) * 8];
      *(short8*)(Cg + (long)(m0 + rowl) * 2048 + c * 8) = v;
    }
#pragma unroll
    for (int x = 0; x < 4; ++x)
#pragma unroll
      for (int r = 0; r < 4; ++r) {
        float s = rs[x][r];
        s += __shfl_xor(s, 1, 64);
        s += __shfl_xor(s, 2, 64);
        s += __shfl_xor(s, 4, 64);
        s += __shfl_xor(s, 8, 64);
        if (fm == 0)
          atomicAdd(&colV[bb * 512 + m0 + wm + x * 16 + fq * 4 + r], s);
      }
  }
}

// ---- rowR: R[b][i] = sum_j E[b][i][j] * rcp(Z[b][j]) (f32, wave-per-row) ---
__global__ __launch_bounds__(256) void rowR(const u16* __restrict__ E,
                                            const float* __restrict__ Z,
                                            float* __restrict__ R) {
  const int id = blockIdx.x;           // 2048 = 8 b (XCD) x 256 row-groups
  const int b = id & 7;
  const int t = threadIdx.x, wave = t >> 6, lane = t & 63;
  const int i = (id >> 3) * 4 + wave;  // 0..1023
  const float* Zb = Z + b * 2048;
  float rz[32];
#pragma unroll
  for (int c = 0; c < 4; ++c) {
    float4 z0 = *(const float4*)(Zb + c * 512 + lane * 8);
    float4 z1 = *(const float4*)(Zb + c * 512 + lane * 8 + 4);
    rz[c * 8 + 0] = __builtin_amdgcn_rcpf(z0.x);
    rz[c * 8 + 1] = __builtin_amdgcn_rcpf(z0.y);
    rz[c * 8 + 2] = __builtin_amdgcn_rcpf(z0.z);
    rz[c * 8 + 3] = __builtin_amdgcn_rcpf(z0.w);
    rz[c * 8 + 4] = __builtin_amdgcn_rcpf(z1.x);
    rz[c * 8 + 5] = __builtin_amdgcn_rcpf(z1.y);
    rz[c * 8 + 6] = __builtin_amdgcn_rcpf(z1.z);
    rz[c * 8 + 7] = __builtin_amdgcn_rcpf(z1.w);
  }
  const u16* Er = E + (long)b * (1024L * 2048) + (long)i * 2048;
  float s = 0.f;
#pragma unroll
  for (int c = 0; c < 4; ++c) {
    short8 v = *(const short8*)(Er + c * 512 + lane * 8);
#pragma unroll
    for (int e = 0; e < 8; ++e) s += bf2f((u16)v[e]) * rz[c * 8 + e];
  }
  s = wave_sum(s);
  if (lane == 0) R[b * 1024 + i] = s;
}

// ------------- scaleV: vT[b][d][j] *= rcp(Z[b][j]), short8/thread -----------
__global__ __launch_bounds__(256) void scaleV(u16* __restrict__ vT,
                                              const float* __restrict__ Z) {
  const long f = ((long)blockIdx.x * 256 + threadIdx.x) * 8;
  const int b = (int)(f >> 20);
  const float* zp = Z + b * 2048 + (int)(f & 2047);
  short8 v = *(const short8*)(vT + f);
  float fv[8];
#pragma unroll
  for (int k = 0; k < 8; ++k)
    fv[k] = bf2f((u16)v[k]) * __builtin_amdgcn_rcpf(zp[k]);
  union { unsigned u[4]; short8 s8; } o;
  o.u[0] = cvt_pk_bf16(fv[0], fv[1]);
  o.u[1] = cvt_pk_bf16(fv[2], fv[3]);
  o.u[2] = cvt_pk_bf16(fv[4], fv[5]);
  o.u[3] = cvt_pk_bf16(fv[6], fv[7]);
  *(short8*)(vT + f) = o.s8;
}

// ------- PV: out[b][i][d] = (sum_j E[i,j]*vT[d,j] + eps*colV[d]) * invR[i] --
// 64x64 tile, BK=128, pure-PV MFMA (R precomputed by rowR). Grid 1024, id&7=b.
__global__ __launch_bounds__(256) void gemm_pv(const u16* __restrict__ E,
    const u16* __restrict__ V, const float* __restrict__ colV,
    const float* __restrict__ R, float* __restrict__ out) {
  __shared__ u16 smem[16384];    // lA 16KB | lB 16KB in K-loop; 64x64 f32 after
  u16* lA = smem;
  u16* lB = smem + 8192;
  const int id = blockIdx.x;
  const int b = id & 7;
  const int m0 = ((id >> 3) & 15) * 64, n0 = (id >> 7) * 64;
  const int t = threadIdx.x, wave = t >> 6, lane = t & 63;
  const int fm = lane & 15, fq = lane >> 4;
  const int wm = (wave >> 1) * 32, wn = (wave & 1) * 32;

  // BK=128 staging: 16 rows x 16 chunks per gload pass; linear LDS dest.
  const int srow = t >> 4;                 // 0..15
  const int swz = ((t & 15) ^ (srow & 15)) * 8;
  const u16* gA = E + (long)b * (1024L * 2048) + (long)(m0 + srow) * 2048 + swz;
  const u16* gB = V + (long)b * (512L * 2048) + (long)(n0 + srow) * 2048 + swz;
  u16* dA = lA + wave * 512;               // 64 lanes x 16B = 1KB = 512 u16
  u16* dB = lB + wave * 512;

  floatx4 acc[2][2];
#pragma unroll
  for (int x = 0; x < 2; ++x)
#pragma unroll
    for (int y = 0; y < 2; ++y) { floatx4 z = {0.f, 0.f, 0.f, 0.f}; acc[x][y] = z; }

#pragma unroll 1
  for (int kt = 0; kt < 16; ++kt) {
    gload16(gA, dA);
    gload16(gA + 16L * 2048, dA + 2048);
    gload16(gA + 32L * 2048, dA + 4096);
    gload16(gA + 48L * 2048, dA + 6144);
    gload16(gB, dB);
    gload16(gB + 16L * 2048, dB + 2048);
    gload16(gB + 32L * 2048, dB + 4096);
    gload16(gB + 48L * 2048, dB + 6144);
    gA += 128; gB += 128;
    __syncthreads();
#pragma unroll
    for (int ks = 0; ks < 4; ++ks) {
      short8 af[2], bfr[2];
      const int chunk = ks * 4 + fq;
      const int csl = (chunk ^ fm) * 8;
#pragma unroll
      for (int x = 0; x < 2; ++x)
        af[x] = *(const short8*)&lA[(wm + x * 16 + fm) * 128 + csl];
#pragma unroll
      for (int y = 0; y < 2; ++y)
        bfr[y] = *(const short8*)&lB[(wn + y * 16 + fm) * 128 + csl];
#pragma unroll
      for (int x = 0; x < 2; ++x)
#pragma unroll
        for (int y = 0; y < 2; ++y)
          acc[x][y] = __builtin_amdgcn_mfma_f32_16x16x32_bf16(af[x], bfr[y], acc[x][y], 0, 0, 0);
    }
    __syncthreads();
  }

  float cv[2];
#pragma unroll
  for (int y = 0; y < 2; ++y) cv[y] = colV[b * 512 + n0 + wn + y * 16 + fm];
  float* sO = (float*)smem;
#pragma unroll
  for (int x = 0; x < 2; ++x)
#pragma unroll
    for (int r = 0; r < 4; ++r) {
      int rowl = wm + x * 16 + fq * 4 + r;
      float invR = __builtin_amdgcn_rcpf(R[b * 1024 + m0 + rowl] + 2048.f * 1e-8f);
#pragma unroll
      for (int y = 0; y < 2; ++y) {
        const int cblk = (wn >> 4) + y;
        sO[rowl * 64 + ((cblk ^ fq) * 16) + fm] =
            (acc[x][y][r] + 1e-8f * cv[y]) * invR;
      }
    }
  __syncthreads();
  float* og = out + (long)b * (1024L * 512);
#pragma unroll
  for (int p = 0; p < 4; ++p) {
    int rowl = p * 16 + (t >> 4);
    int c = t & 15;
    int q = (rowl >> 2) & 3;
    float4 v = *(const float4*)&sO[rowl * 64 + (((c >> 2) ^ q) * 16) + (c & 3) * 4];
    *(float4*)(og + (long)(m0 + rowl) * 512 + n0 + c * 4) = v;
  }
}

extern "C" void kernel_launch(void* const* d_in, const int* in_sizes, int n_in,
                              void* d_out, int out_size, void* d_ws, size_t ws_size,
                              hipStream_t stream) {
  const float* inputs  = (const float*)d_in[0];
  const float* context = (const float*)d_in[1];
  const float* ln_in_g = (const float*)d_in[2];
  const float* ln_in_b = (const float*)d_in[3];
  const float* ln_ctx_g = (const float*)d_in[4];
  const float* ln_ctx_b = (const float*)d_in[5];
  const float* Wq = (const float*)d_in[6];
  const float* bq = (const float*)d_in[7];
  const float* Wk = (const float*)d_in[8];
  const float* bk = (const float*)d_in[9];
  const float* Wv = (const float*)d_in[10];
  const float* bv = (const float*)d_in[11];
  float* out = (float*)d_out;

  u16* ws = (u16*)d_ws;
  u16* xb  = ws;                        // [8192][512]
  u16* qb  = xb + 8192L * 512;          // [8192][512]
  u16* cb  = qb + 8192L * 512;          // [16384][512]
  u16* wqb = cb + 16384L * 512;         // [512][512]
  u16* wkb = wqb + 512L * 512;
  u16* wvb = wkb + 512L * 512;
  u16* kb  = wvb + 512L * 512;          // [16384][512]
  u16* vTs = kb + 16384L * 512;         // [8][512][2048]
  u16* E   = vTs + 8L * 512 * 2048;     // [8][1024][2048]
  float* Z    = (float*)(E + 8L * 1024 * 2048);   // [8][2048] raw col sums
  float* colV = Z + 8L * 2048;                    // [8][512]
  float* Rr   = colV + 8L * 512;                  // [8][1024] row renorm sums

  // 512^-0.5 * log2(e): fold scale AND exp->exp2 factor into Wq/bq
  const float qsc = (float)(0.04419417382415922 * 1.4426950408889634);

  // 1: LN(inputs)+LN(context) wave-per-row + weight cvt + zero Z/colV
  ln_prep<<<6932, 256, 0, stream>>>(inputs, ln_in_g, ln_in_b, xb,
                                    context, ln_ctx_g, ln_ctx_b, cb,
                                    Wq, Wk, Wv, wqb, wkb, wvb, Z, qsc);
  // 2: q-proj (bx<64, bias*qsc) + k-proj (bx>=64)
  gemm_proj<<<dim3(192, 4, 1), 256, 0, stream>>>(xb, wqb, bq, qb,
                                                 cb, wkb, bk, kb, qsc, 1.f);
  // 3: merged QK (E, Z) + v-projT unscaled (vT, colV)
  qk_vproj<<<1536, 256, 0, stream>>>(qb, kb, E, Z, wvb, cb, bv, vTs, colV);
  // 4a: R[b][i] = sum_j E*rcpZ (f32 matrix-vector, replaces PV's inline-R)
  rowR<<<2048, 256, 0, stream>>>(E, Z, Rr);
  // 4b: vT *= rcp(Z)
  scaleV<<<4096, 256, 0, stream>>>(vTs, Z);
  // 5: PV 64x64 tile, BK=128, pure MFMA (R from rowR)
  gemm_pv<<<1024, 256, 0, stream>>>(E, vTs, colV, Rr, out);
}

// Round 7
// 204.325 us; speedup vs baseline: 1.0311x; 1.0311x over previous
//
#include <hip/hip_runtime.h>

using u16 = unsigned short;
typedef __attribute__((ext_vector_type(8))) short short8;
typedef __attribute__((ext_vector_type(4))) float floatx4;

#define NQ 1024
#define NK 2048
#define DD 512

__device__ __forceinline__ float bf2f(u16 u) {
  union { unsigned u; float f; } x; x.u = ((unsigned)u) << 16; return x.f;
}
// packed RTNE f32x2 -> bf16x2 (bits[15:0]=lo, [31:16]=hi)
__device__ __forceinline__ unsigned cvt_pk_bf16(float lo, float hi) {
  unsigned r;
  asm("v_cvt_pk_bf16_f32 %0, %1, %2" : "=v"(r) : "v"(lo), "v"(hi));
  return r;
}
__device__ __forceinline__ float wave_sum(float v) {
#pragma unroll
  for (int off = 32; off > 0; off >>= 1) v += __shfl_down(v, off, 64);
  return v;
}
__device__ __forceinline__ void gload16(const u16* g, const u16* l) {
  __builtin_amdgcn_global_load_lds(
      (const __attribute__((address_space(1))) void*)g,
      (__attribute__((address_space(3))) void*)l, 16, 0, 0);
}

// ---- fused: wave-per-row LN (inputs+context) + weight cvt + zero Z/colV ----
// Wq/bq are pre-scaled by qsc = 512^-0.5 * log2(e) so QK epilogue is exp2(acc).
__global__ __launch_bounds__(256) void ln_prep(
    const float* __restrict__ X1, const float* __restrict__ G1,
    const float* __restrict__ B1, u16* __restrict__ Y1,
    const float* __restrict__ X2, const float* __restrict__ G2,
    const float* __restrict__ B2, u16* __restrict__ Y2,
    const float* __restrict__ Wq, const float* __restrict__ Wk,
    const float* __restrict__ Wv, u16* __restrict__ wqb,
    u16* __restrict__ wkb, u16* __restrict__ wvb, float* __restrict__ Zero,
    float qsc) {
  const int bx = blockIdx.x;
  const int t = threadIdx.x;
  if (bx >= 6144) {
    int e = bx - 6144;
    if (e < 768) {
      const float* src = e < 256 ? Wq : (e < 512 ? Wk : Wv);
      u16* dst = e < 256 ? wqb : (e < 512 ? wkb : wvb);
      const float ws = e < 256 ? qsc : 1.f;
      int i = ((e & 255) * 256 + t) * 4;
      float4 v = *(const float4*)(src + i);
      union { unsigned u[2]; ushort4 s; } ou;
      ou.u[0] = cvt_pk_bf16(v.x * ws, v.y * ws);
      ou.u[1] = cvt_pk_bf16(v.z * ws, v.w * ws);
      *(ushort4*)(dst + i) = ou.s;
    } else {
      int i = ((e - 768) * 256 + t) * 4;
      float4 z = {0.f, 0.f, 0.f, 0.f};
      *(float4*)(Zero + i) = z;
    }
    return;
  }
  const int wave = t >> 6, lane = t & 63;
  int row = bx * 4 + wave;
  const float *X, *G, *Bv; u16* Y;
  if (row < 8192) { X = X1; G = G1; Bv = B1; Y = Y1; }
  else { row -= 8192; X = X2; G = G2; Bv = B2; Y = Y2; }
  const float4* Xp = (const float4*)(X + (long)row * DD);
  float4 v0 = Xp[lane * 2], v1 = Xp[lane * 2 + 1];
  float s = v0.x + v0.y + v0.z + v0.w + v1.x + v1.y + v1.z + v1.w;
  float ss = v0.x * v0.x + v0.y * v0.y + v0.z * v0.z + v0.w * v0.w +
             v1.x * v1.x + v1.y * v1.y + v1.z * v1.z + v1.w * v1.w;
  s = wave_sum(s);  s = __shfl(s, 0, 64);
  ss = wave_sum(ss); ss = __shfl(ss, 0, 64);
  float mu = s * (1.f / DD);
  float var = ss * (1.f / DD) - mu * mu;
  float rs = rsqrtf(var + 1e-5f);
  const float4* Gp = (const float4*)G;
  const float4* Bp = (const float4*)Bv;
  float4 g0 = Gp[lane * 2], g1 = Gp[lane * 2 + 1];
  float4 b0 = Bp[lane * 2], b1 = Bp[lane * 2 + 1];
  union { unsigned u[4]; short8 s8; } ou;
  ou.u[0] = cvt_pk_bf16((v0.x - mu) * rs * g0.x + b0.x,
                        (v0.y - mu) * rs * g0.y + b0.y);
  ou.u[1] = cvt_pk_bf16((v0.z - mu) * rs * g0.z + b0.z,
                        (v0.w - mu) * rs * g0.w + b0.w);
  ou.u[2] = cvt_pk_bf16((v1.x - mu) * rs * g1.x + b1.x,
                        (v1.y - mu) * rs * g1.y + b1.y);
  ou.u[3] = cvt_pk_bf16((v1.z - mu) * rs * g1.z + b1.z,
                        (v1.w - mu) * rs * g1.w + b1.w);
  *(short8*)(Y + (long)row * DD + lane * 8) = ou.s8;
}

// ---------- q-proj + k-proj (B^T GEMM, K=512, BK=64, swizzled LDS) ----------
__global__ __launch_bounds__(256) void gemm_proj(
    const u16* __restrict__ A1, const u16* __restrict__ W1,
    const float* __restrict__ b1, u16* __restrict__ C1,
    const u16* __restrict__ A2, const u16* __restrict__ W2,
    const float* __restrict__ b2, u16* __restrict__ C2,
    float bsc1, float bsc2) {
  __shared__ u16 smem[16384];   // lA | lB in K-loop; 128x128 C-tile in epilogue
  u16* lA = smem;
  u16* lB = smem + 8192;
  const u16 *A, *B; const float* bias; u16* Cout; float bsc;
  int m0 = blockIdx.x * 128;
  if (blockIdx.x < 64) { A = A1; B = W1; bias = b1; Cout = C1; bsc = bsc1; }
  else { A = A2; B = W2; bias = b2; Cout = C2; bsc = bsc2;
         m0 = (blockIdx.x - 64) * 128; }
  const int n0 = blockIdx.y * 128;
  const int t = threadIdx.x, wave = t >> 6, lane = t & 63;
  const int fm = lane & 15, fq = lane >> 4;
  const int wm = (wave >> 1) * 64, wn = (wave & 1) * 64;

  const int srow = t >> 3;
  const int swz = ((t & 7) ^ (srow & 7)) * 8;
  const u16* gA = A + (long)(m0 + srow) * 512 + swz;
  const u16* gB = B + (long)(n0 + srow) * 512 + swz;
  u16* dA = lA + wave * 512;
  u16* dB = lB + wave * 512;

  floatx4 acc[4][4];
#pragma unroll
  for (int x = 0; x < 4; ++x)
#pragma unroll
    for (int y = 0; y < 4; ++y) { floatx4 z = {0.f, 0.f, 0.f, 0.f}; acc[x][y] = z; }

#pragma unroll 1
  for (int kt = 0; kt < 8; ++kt) {
    gload16(gA, dA);
    gload16(gA + 32L * 512, dA + 2048);
    gload16(gA + 64L * 512, dA + 4096);
    gload16(gA + 96L * 512, dA + 6144);
    gload16(gB, dB);
    gload16(gB + 32L * 512, dB + 2048);
    gload16(gB + 64L * 512, dB + 4096);
    gload16(gB + 96L * 512, dB + 6144);
    gA += 64; gB += 64;
    __syncthreads();
#pragma unroll
    for (int ks = 0; ks < 2; ++ks) {
      short8 af[4], bfr[4];
      const int csl = ((ks * 4 + fq) ^ (fm & 7)) * 8;
#pragma unroll
      for (int x = 0; x < 4; ++x)
        af[x] = *(const short8*)&lA[(wm + x * 16 + fm) * 64 + csl];
#pragma unroll
      for (int y = 0; y < 4; ++y)
        bfr[y] = *(const short8*)&lB[(wn + y * 16 + fm) * 64 + csl];
#pragma unroll
      for (int x = 0; x < 4; ++x)
#pragma unroll
        for (int y = 0; y < 4; ++y)
          acc[x][y] = __builtin_amdgcn_mfma_f32_16x16x32_bf16(af[x], bfr[y], acc[x][y], 0, 0, 0);
    }
    __syncthreads();
  }

  float bs[4];
  int cs[4];
#pragma unroll
  for (int y = 0; y < 4; ++y) {
    bs[y] = bias[n0 + wn + y * 16 + fm] * bsc;
    cs[y] = ((((wn >> 4) + y) ^ fq) * 16) + fm;
  }
#pragma unroll
  for (int x = 0; x < 4; ++x)
#pragma unroll
    for (int r = 0; r < 4; ++r) {
      int rowl = wm + x * 16 + fq * 4 + r;
      unsigned p01 = cvt_pk_bf16(acc[x][0][r] + bs[0], acc[x][1][r] + bs[1]);
      unsigned p23 = cvt_pk_bf16(acc[x][2][r] + bs[2], acc[x][3][r] + bs[3]);
      smem[rowl * 128 + cs[0]] = (u16)p01;
      smem[rowl * 128 + cs[1]] = (u16)(p01 >> 16);
      smem[rowl * 128 + cs[2]] = (u16)p23;
      smem[rowl * 128 + cs[3]] = (u16)(p23 >> 16);
    }
  __syncthreads();
#pragma unroll
  for (int p = 0; p < 8; ++p) {
    int rowl = p * 16 + (t >> 4);
    int c = t & 15;
    int q = (rowl >> 2) & 3;
    short8 v = *(const short8*)&smem[rowl * 128 + (((c >> 1) ^ q) * 16) + (c & 1) * 8];
    *(short8*)(Cout + (long)(m0 + rowl) * 512 + n0 + c * 8) = v;
  }
}

// ------- merged: QK (blocks 0..1023) + v-projT unscaled (1024..1535) --------
// qb is pre-scaled so E = exp2(acc) directly.
__global__ __launch_bounds__(256) void qk_vproj(
    const u16* __restrict__ qb, const u16* __restrict__ kb,
    u16* __restrict__ E, float* __restrict__ Z,
    const u16* __restrict__ wvb, const u16* __restrict__ cb,
    const float* __restrict__ bv, u16* __restrict__ vT,
    float* __restrict__ colV) {
  __shared__ u16 smem[16384];
  __shared__ float colred[128];
  u16* lA = smem;
  u16* lB = smem + 8192;

  const int bx = blockIdx.x;
  const bool is_qk = bx < 1024;
  const u16 *A, *B;
  int m0, n0, b;
  if (is_qk) {
    b = bx & 7;
    n0 = ((bx >> 3) & 15) * 128;
    m0 = (bx >> 7) * 128;
    A = qb + (long)b * (1024L * 512);
    B = kb + (long)b * (2048L * 512);
  } else {
    int e = bx - 1024;
    m0 = (e & 3) * 128;
    n0 = (e >> 2) * 128;
    b = 0;
    A = wvb;
    B = cb;
  }
  const int t = threadIdx.x, wave = t >> 6, lane = t & 63;
  const int fm = lane & 15, fq = lane >> 4;
  const int wm = (wave >> 1) * 64, wn = (wave & 1) * 64;

  const int srow = t >> 3;
  const int swz = ((t & 7) ^ (srow & 7)) * 8;
  const u16* gA = A + (long)(m0 + srow) * 512 + swz;
  const u16* gB = B + (long)(n0 + srow) * 512 + swz;
  u16* dA = lA + wave * 512;
  u16* dB = lB + wave * 512;

  floatx4 acc[4][4];
#pragma unroll
  for (int x = 0; x < 4; ++x)
#pragma unroll
    for (int y = 0; y < 4; ++y) { floatx4 z = {0.f, 0.f, 0.f, 0.f}; acc[x][y] = z; }

#pragma unroll 1
  for (int kt = 0; kt < 8; ++kt) {
    gload16(gA, dA);
    gload16(gA + 32L * 512, dA + 2048);
    gload16(gA + 64L * 512, dA + 4096);
    gload16(gA + 96L * 512, dA + 6144);
    gload16(gB, dB);
    gload16(gB + 32L * 512, dB + 2048);
    gload16(gB + 64L * 512, dB + 4096);
    gload16(gB + 96L * 512, dB + 6144);
    gA += 64; gB += 64;
    __syncthreads();
#pragma unroll
    for (int ks = 0; ks < 2; ++ks) {
      short8 af[4], bfr[4];
      const int csl = ((ks * 4 + fq) ^ (fm & 7)) * 8;
#pragma unroll
      for (int x = 0; x < 4; ++x)
        af[x] = *(const short8*)&lA[(wm + x * 16 + fm) * 64 + csl];
#pragma unroll
      for (int y = 0; y < 4; ++y)
        bfr[y] = *(const short8*)&lB[(wn + y * 16 + fm) * 64 + csl];
#pragma unroll
      for (int x = 0; x < 4; ++x)
#pragma unroll
        for (int y = 0; y < 4; ++y)
          acc[x][y] = __builtin_amdgcn_mfma_f32_16x16x32_bf16(af[x], bfr[y], acc[x][y], 0, 0, 0);
    }
    __syncthreads();
  }

  int cs[4];
#pragma unroll
  for (int y = 0; y < 4; ++y) cs[y] = ((((wn >> 4) + y) ^ fq) * 16) + fm;

  if (is_qk) {
    float s4[4] = {0.f, 0.f, 0.f, 0.f};
#pragma unroll
    for (int x = 0; x < 4; ++x)
#pragma unroll
      for (int r = 0; r < 4; ++r) {
        int rowl = wm + x * 16 + fq * 4 + r;
        float e0 = __builtin_amdgcn_exp2f(acc[x][0][r]);
        float e1 = __builtin_amdgcn_exp2f(acc[x][1][r]);
        float e2 = __builtin_amdgcn_exp2f(acc[x][2][r]);
        float e3 = __builtin_amdgcn_exp2f(acc[x][3][r]);
        s4[0] += e0; s4[1] += e1; s4[2] += e2; s4[3] += e3;
        unsigned p01 = cvt_pk_bf16(e0, e1);
        unsigned p23 = cvt_pk_bf16(e2, e3);
        smem[rowl * 128 + cs[0]] = (u16)p01;
        smem[rowl * 128 + cs[1]] = (u16)(p01 >> 16);
        smem[rowl * 128 + cs[2]] = (u16)p23;
        smem[rowl * 128 + cs[3]] = (u16)(p23 >> 16);
      }
#pragma unroll
    for (int y = 0; y < 4; ++y) {
      s4[y] += __shfl_xor(s4[y], 16, 64);
      s4[y] += __shfl_xor(s4[y], 32, 64);
    }
    if (t < 128) colred[t] = 0.f;
    __syncthreads();
    u16* Eg = E + (long)b * (1024L * 2048);
#pragma unroll
    for (int p = 0; p < 8; ++p) {
      int rowl = p * 16 + (t >> 4);
      int c = t & 15;
      int q = (rowl >> 2) & 3;
      short8 v = *(const short8*)&smem[rowl * 128 + (((c >> 1) ^ q) * 16) + (c & 1) * 8];
      *(short8*)(Eg + (long)(m0 + rowl) * 2048 + n0 + c * 8) = v;
    }
    if (fq == 0) {
#pragma unroll
      for (int y = 0; y < 4; ++y) atomicAdd(&colred[wn + y * 16 + fm], s4[y]);
    }
    __syncthreads();
    if (t < 128) atomicAdd(&Z[b * 2048 + n0 + t], colred[t]);
  } else {
    const int bb = n0 >> 11;
    const int j0c = n0 & 2047;
    float bsr[4][4];
#pragma unroll
    for (int x = 0; x < 4; ++x)
#pragma unroll
      for (int r = 0; r < 4; ++r)
        bsr[x][r] = bv[m0 + wm + x * 16 + fq * 4 + r];
    float rs[4][4];
#pragma unroll
    for (int x = 0; x < 4; ++x)
#pragma unroll
      for (int r = 0; r < 4; ++r) rs[x][r] = 0.f;
#pragma unroll
    for (int x = 0; x < 4; ++x)
#pragma unroll
      for (int r = 0; r < 4; ++r) {
        int rowl = wm + x * 16 + fq * 4 + r;
        float v0 = acc[x][0][r] + bsr[x][r];
        float v1 = acc[x][1][r] + bsr[x][r];
        float v2 = acc[x][2][r] + bsr[x][r];
        float v3 = acc[x][3][r] + bsr[x][r];
        rs[x][r] += v0 + v1 + v2 + v3;
        unsigned p01 = cvt_pk_bf16(v0, v1);
        unsigned p23 = cvt_pk_bf16(v2, v3);
        smem[rowl * 128 + cs[0]] = (u16)p01;
        smem[rowl * 128 + cs[1]] = (u16)(p01 >> 16);
        smem[rowl * 128 + cs[2]] = (u16)p23;
        smem[rowl * 128 + cs[3]] = (u16)(p23 >> 16);
      }
    __syncthreads();
    u16* Cg = vT + (long)bb * (512L * 2048) + j0c;
#pragma unroll
    for (int p = 0; p < 8; ++p) {
      int rowl = p * 16 + (t >> 4);
      int c = t & 15;
      int q = (rowl >> 2) & 3;
      short8 v = *(const short8*)&smem[rowl * 128 + (((c >> 1) ^ q) * 16) + (c & 1) * 8];
      *(short8*)(Cg + (long)(m0 + rowl) * 2048 + c * 8) = v;
    }
#pragma unroll
    for (int x = 0; x < 4; ++x)
#pragma unroll
      for (int r = 0; r < 4; ++r) {
        float s = rs[x][r];
        s += __shfl_xor(s, 1, 64);
        s += __shfl_xor(s, 2, 64);
        s += __shfl_xor(s, 4, 64);
        s += __shfl_xor(s, 8, 64);
        if (fm == 0)
          atomicAdd(&colV[bb * 512 + m0 + wm + x * 16 + fq * 4 + r], s);
      }
  }
}

// ------- PV: out[b][i][d] = (sum_j E[i,j]*vT[d,j]/Z[j] + eps*colV[d])*invR --
// 64x64 tile, BK=64, inline R via accR MFMA (proven free). V is staged from
// registers with inline 1/Z scaling -> scaleV kernel eliminated. LDS dest/lane
// pattern byte-identical to the gload16 path it replaces.
__global__ __launch_bounds__(256) void gemm_pv(const u16* __restrict__ E,
    const u16* __restrict__ V, const float* __restrict__ colV,
    const float* __restrict__ Z, float* __restrict__ out) {
  __shared__ u16 smem[8192];     // lA | lB in K-loop; 64x64 fp32 tile after
  __shared__ u16 sZb[2048];
  u16* lA = smem;
  u16* lB = smem + 4096;
  const int id = blockIdx.x;
  const int b = id & 7;
  const int m0 = ((id >> 3) & 15) * 64, n0 = (id >> 7) * 64;
  const int t = threadIdx.x, wave = t >> 6, lane = t & 63;
  const int fm = lane & 15, fq = lane >> 4;
  const int wm = (wave >> 1) * 32, wn = (wave & 1) * 32;

  {
    int i = t * 8;
    float4 z0 = *(const float4*)(Z + b * 2048 + i);
    float4 z1 = *(const float4*)(Z + b * 2048 + i + 4);
    union { unsigned u[4]; short8 s8; } o;
    o.u[0] = cvt_pk_bf16(__builtin_amdgcn_rcpf(z0.x), __builtin_amdgcn_rcpf(z0.y));
    o.u[1] = cvt_pk_bf16(__builtin_amdgcn_rcpf(z0.z), __builtin_amdgcn_rcpf(z0.w));
    o.u[2] = cvt_pk_bf16(__builtin_amdgcn_rcpf(z1.x), __builtin_amdgcn_rcpf(z1.y));
    o.u[3] = cvt_pk_bf16(__builtin_amdgcn_rcpf(z1.z), __builtin_amdgcn_rcpf(z1.w));
    *(short8*)&sZb[i] = o.s8;
  }
  __syncthreads();   // staging below reads sZb

  const int srow = t >> 3;
  const int swz = ((t & 7) ^ (srow & 7)) * 8;
  const u16* gA = E + (long)b * (1024L * 2048) + (long)(m0 + srow) * 2048 + swz;
  const u16* gB = V + (long)b * (512L * 2048) + (long)(n0 + srow) * 2048 + swz;
  u16* dA = lA + wave * 512;
  u16* dB = lB + wave * 512;

  floatx4 acc[2][2];
  floatx4 accR[2];
#pragma unroll
  for (int x = 0; x < 2; ++x) {
    floatx4 z = {0.f, 0.f, 0.f, 0.f};
    accR[x] = z;
#pragma unroll
    for (int y = 0; y < 2; ++y) acc[x][y] = z;
  }

#pragma unroll 1
  for (int kt = 0; kt < 32; ++kt) {
    // V: reg-stage with inline 1/Z column scaling (was scaleV + gload16)
    short8 rv0 = *(const short8*)gB;
    short8 rv1 = *(const short8*)(gB + 32L * 2048);
    gload16(gA, dA);
    gload16(gA + 32L * 2048, dA + 2048);
    short8 zr = *(const short8*)&sZb[kt * 64 + swz];
    float zf8[8];
#pragma unroll
    for (int e = 0; e < 8; ++e) zf8[e] = bf2f((u16)zr[e]);
    union { unsigned u[4]; short8 s8; } o0, o1;
#pragma unroll
    for (int e = 0; e < 4; ++e) {
      o0.u[e] = cvt_pk_bf16(bf2f((u16)rv0[2 * e]) * zf8[2 * e],
                            bf2f((u16)rv0[2 * e + 1]) * zf8[2 * e + 1]);
      o1.u[e] = cvt_pk_bf16(bf2f((u16)rv1[2 * e]) * zf8[2 * e],
                            bf2f((u16)rv1[2 * e + 1]) * zf8[2 * e + 1]);
    }
    u16* db = dB + (lane << 3);
    *(short8*)db = o0.s8;
    *(short8*)(db + 2048) = o1.s8;
    gA += 64; gB += 64;
    __syncthreads();
#pragma unroll
    for (int ks = 0; ks < 2; ++ks) {
      short8 af[2], bfr[2];
      const int chunk = ks * 4 + fq;
      const int csl = (chunk ^ (fm & 7)) * 8;
#pragma unroll
      for (int x = 0; x < 2; ++x)
        af[x] = *(const short8*)&lA[(wm + x * 16 + fm) * 64 + csl];
#pragma unroll
      for (int y = 0; y < 2; ++y)
        bfr[y] = *(const short8*)&lB[(wn + y * 16 + fm) * 64 + csl];
      short8 zf = *(const short8*)&sZb[kt * 64 + chunk * 8];
#pragma unroll
      for (int x = 0; x < 2; ++x) {
#pragma unroll
        for (int y = 0; y < 2; ++y)
          acc[x][y] = __builtin_amdgcn_mfma_f32_16x16x32_bf16(af[x], bfr[y], acc[x][y], 0, 0, 0);
        accR[x] = __builtin_amdgcn_mfma_f32_16x16x32_bf16(af[x], zf, accR[x], 0, 0, 0);
      }
    }
    __syncthreads();
  }

  float cv[2];
#pragma unroll
  for (int y = 0; y < 2; ++y) cv[y] = colV[b * 512 + n0 + wn + y * 16 + fm];
  float* sO = (float*)smem;
#pragma unroll
  for (int x = 0; x < 2; ++x)
#pragma unroll
    for (int r = 0; r < 4; ++r) {
      float invR = __builtin_amdgcn_rcpf(accR[x][r] + 2048.f * 1e-8f);
      int rowl = wm + x * 16 + fq * 4 + r;
#pragma unroll
      for (int y = 0; y < 2; ++y) {
        const int cblk = (wn >> 4) + y;
        sO[rowl * 64 + ((cblk ^ fq) * 16) + fm] =
            (acc[x][y][r] + 1e-8f * cv[y]) * invR;
      }
    }
  __syncthreads();
  float* og = out + (long)b * (1024L * 512);
#pragma unroll
  for (int p = 0; p < 4; ++p) {
    int rowl = p * 16 + (t >> 4);
    int c = t & 15;
    int q = (rowl >> 2) & 3;
    float4 v = *(const float4*)&sO[rowl * 64 + (((c >> 2) ^ q) * 16) + (c & 3) * 4];
    *(float4*)(og + (long)(m0 + rowl) * 512 + n0 + c * 4) = v;
  }
}

extern "C" void kernel_launch(void* const* d_in, const int* in_sizes, int n_in,
                              void* d_out, int out_size, void* d_ws, size_t ws_size,
                              hipStream_t stream) {
  const float* inputs  = (const float*)d_in[0];
  const float* context = (const float*)d_in[1];
  const float* ln_in_g = (const float*)d_in[2];
  const float* ln_in_b = (const float*)d_in[3];
  const float* ln_ctx_g = (const float*)d_in[4];
  const float* ln_ctx_b = (const float*)d_in[5];
  const float* Wq = (const float*)d_in[6];
  const float* bq = (const float*)d_in[7];
  const float* Wk = (const float*)d_in[8];
  const float* bk = (const float*)d_in[9];
  const float* Wv = (const float*)d_in[10];
  const float* bv = (const float*)d_in[11];
  float* out = (float*)d_out;

  u16* ws = (u16*)d_ws;
  u16* xb  = ws;                        // [8192][512]
  u16* qb  = xb + 8192L * 512;          // [8192][512]
  u16* cb  = qb + 8192L * 512;          // [16384][512]
  u16* wqb = cb + 16384L * 512;         // [512][512]
  u16* wkb = wqb + 512L * 512;
  u16* wvb = wkb + 512L * 512;
  u16* kb  = wvb + 512L * 512;          // [16384][512]
  u16* vTs = kb + 16384L * 512;         // [8][512][2048] raw (unscaled)
  u16* E   = vTs + 8L * 512 * 2048;     // [8][1024][2048]
  float* Z    = (float*)(E + 8L * 1024 * 2048);   // [8][2048] raw col sums
  float* colV = Z + 8L * 2048;                    // [8][512]

  // 512^-0.5 * log2(e): fold scale AND exp->exp2 factor into Wq/bq
  const float qsc = (float)(0.04419417382415922 * 1.4426950408889634);

  // 1: LN(inputs)+LN(context) wave-per-row + weight cvt + zero Z/colV
  ln_prep<<<6932, 256, 0, stream>>>(inputs, ln_in_g, ln_in_b, xb,
                                    context, ln_ctx_g, ln_ctx_b, cb,
                                    Wq, Wk, Wv, wqb, wkb, wvb, Z, qsc);
  // 2: q-proj (bx<64, bias*qsc) + k-proj (bx>=64)
  gemm_proj<<<dim3(192, 4, 1), 256, 0, stream>>>(xb, wqb, bq, qb,
                                                 cb, wkb, bk, kb, qsc, 1.f);
  // 3: merged QK (E, Z) + v-projT unscaled (vT, colV)
  qk_vproj<<<1536, 256, 0, stream>>>(qb, kb, E, Z, wvb, cb, bv, vTs, colV);
  // 4: PV with inline R and inline 1/Z V-scaling (scaleV + rowR eliminated)
  gemm_pv<<<1024, 256, 0, stream>>>(E, vTs, colV, Z, out);
}

// Round 9
// 204.202 us; speedup vs baseline: 1.0318x; 1.0006x over previous
//
#include <hip/hip_runtime.h>

using u16 = unsigned short;
typedef __attribute__((ext_vector_type(8))) short short8;
typedef __attribute__((ext_vector_type(4))) float floatx4;

#define NQ 1024
#define NK 2048
#define DD 512

__device__ __forceinline__ float bf2f(u16 u) {
  union { unsigned u; float f; } x; x.u = ((unsigned)u) << 16; return x.f;
}
// packed RTNE f32x2 -> bf16x2 (bits[15:0]=lo, [31:16]=hi)
__device__ __forceinline__ unsigned cvt_pk_bf16(float lo, float hi) {
  unsigned r;
  asm("v_cvt_pk_bf16_f32 %0, %1, %2" : "=v"(r) : "v"(lo), "v"(hi));
  return r;
}
__device__ __forceinline__ float wave_sum(float v) {
#pragma unroll
  for (int off = 32; off > 0; off >>= 1) v += __shfl_down(v, off, 64);
  return v;
}
__device__ __forceinline__ void gload16(const u16* g, const u16* l) {
  __builtin_amdgcn_global_load_lds(
      (const __attribute__((address_space(1))) void*)g,
      (__attribute__((address_space(3))) void*)l, 16, 0, 0);
}

// ---- fused: wave-per-row LN (inputs+context) + weight cvt + zero Z/colV ----
// Wq/bq are pre-scaled by qsc = 512^-0.5 * log2(e) so QK epilogue is exp2(acc).
__global__ __launch_bounds__(256) void ln_prep(
    const float* __restrict__ X1, const float* __restrict__ G1,
    const float* __restrict__ B1, u16* __restrict__ Y1,
    const float* __restrict__ X2, const float* __restrict__ G2,
    const float* __restrict__ B2, u16* __restrict__ Y2,
    const float* __restrict__ Wq, const float* __restrict__ Wk,
    const float* __restrict__ Wv, u16* __restrict__ wqb,
    u16* __restrict__ wkb, u16* __restrict__ wvb, float* __restrict__ Zero,
    float qsc) {
  const int bx = blockIdx.x;
  const int t = threadIdx.x;
  if (bx >= 6144) {
    int e = bx - 6144;
    if (e < 768) {
      const float* src = e < 256 ? Wq : (e < 512 ? Wk : Wv);
      u16* dst = e < 256 ? wqb : (e < 512 ? wkb : wvb);
      const float ws = e < 256 ? qsc : 1.f;
      int i = ((e & 255) * 256 + t) * 4;
      float4 v = *(const float4*)(src + i);
      union { unsigned u[2]; ushort4 s; } ou;
      ou.u[0] = cvt_pk_bf16(v.x * ws, v.y * ws);
      ou.u[1] = cvt_pk_bf16(v.z * ws, v.w * ws);
      *(ushort4*)(dst + i) = ou.s;
    } else {
      int i = ((e - 768) * 256 + t) * 4;
      float4 z = {0.f, 0.f, 0.f, 0.f};
      *(float4*)(Zero + i) = z;
    }
    return;
  }
  const int wave = t >> 6, lane = t & 63;
  int row = bx * 4 + wave;
  const float *X, *G, *Bv; u16* Y;
  if (row < 8192) { X = X1; G = G1; Bv = B1; Y = Y1; }
  else { row -= 8192; X = X2; G = G2; Bv = B2; Y = Y2; }
  const float4* Xp = (const float4*)(X + (long)row * DD);
  float4 v0 = Xp[lane * 2], v1 = Xp[lane * 2 + 1];
  float s = v0.x + v0.y + v0.z + v0.w + v1.x + v1.y + v1.z + v1.w;
  float ss = v0.x * v0.x + v0.y * v0.y + v0.z * v0.z + v0.w * v0.w +
             v1.x * v1.x + v1.y * v1.y + v1.z * v1.z + v1.w * v1.w;
  s = wave_sum(s);  s = __shfl(s, 0, 64);
  ss = wave_sum(ss); ss = __shfl(ss, 0, 64);
  float mu = s * (1.f / DD);
  float var = ss * (1.f / DD) - mu * mu;
  float rs = rsqrtf(var + 1e-5f);
  const float4* Gp = (const float4*)G;
  const float4* Bp = (const float4*)Bv;
  float4 g0 = Gp[lane * 2], g1 = Gp[lane * 2 + 1];
  float4 b0 = Bp[lane * 2], b1 = Bp[lane * 2 + 1];
  union { unsigned u[4]; short8 s8; } ou;
  ou.u[0] = cvt_pk_bf16((v0.x - mu) * rs * g0.x + b0.x,
                        (v0.y - mu) * rs * g0.y + b0.y);
  ou.u[1] = cvt_pk_bf16((v0.z - mu) * rs * g0.z + b0.z,
                        (v0.w - mu) * rs * g0.w + b0.w);
  ou.u[2] = cvt_pk_bf16((v1.x - mu) * rs * g1.x + b1.x,
                        (v1.y - mu) * rs * g1.y + b1.y);
  ou.u[3] = cvt_pk_bf16((v1.z - mu) * rs * g1.z + b1.z,
                        (v1.w - mu) * rs * g1.w + b1.w);
  *(short8*)(Y + (long)row * DD + lane * 8) = ou.s8;
}

// ---------- q-proj + k-proj (B^T GEMM, K=512, BK=64, swizzled LDS) ----------
__global__ __launch_bounds__(256) void gemm_proj(
    const u16* __restrict__ A1, const u16* __restrict__ W1,
    const float* __restrict__ b1, u16* __restrict__ C1,
    const u16* __restrict__ A2, const u16* __restrict__ W2,
    const float* __restrict__ b2, u16* __restrict__ C2,
    float bsc1, float bsc2) {
  __shared__ u16 smem[16384];   // lA | lB in K-loop; 128x128 C-tile in epilogue
  u16* lA = smem;
  u16* lB = smem + 8192;
  const u16 *A, *B; const float* bias; u16* Cout; float bsc;
  int m0 = blockIdx.x * 128;
  if (blockIdx.x < 64) { A = A1; B = W1; bias = b1; Cout = C1; bsc = bsc1; }
  else { A = A2; B = W2; bias = b2; Cout = C2; bsc = bsc2;
         m0 = (blockIdx.x - 64) * 128; }
  const int n0 = blockIdx.y * 128;
  const int t = threadIdx.x, wave = t >> 6, lane = t & 63;
  const int fm = lane & 15, fq = lane >> 4;
  const int wm = (wave >> 1) * 64, wn = (wave & 1) * 64;

  const int srow = t >> 3;
  const int swz = ((t & 7) ^ (srow & 7)) * 8;
  const u16* gA = A + (long)(m0 + srow) * 512 + swz;
  const u16* gB = B + (long)(n0 + srow) * 512 + swz;
  u16* dA = lA + wave * 512;
  u16* dB = lB + wave * 512;

  floatx4 acc[4][4];
#pragma unroll
  for (int x = 0; x < 4; ++x)
#pragma unroll
    for (int y = 0; y < 4; ++y) { floatx4 z = {0.f, 0.f, 0.f, 0.f}; acc[x][y] = z; }

#pragma unroll 1
  for (int kt = 0; kt < 8; ++kt) {
    gload16(gA, dA);
    gload16(gA + 32L * 512, dA + 2048);
    gload16(gA + 64L * 512, dA + 4096);
    gload16(gA + 96L * 512, dA + 6144);
    gload16(gB, dB);
    gload16(gB + 32L * 512, dB + 2048);
    gload16(gB + 64L * 512, dB + 4096);
    gload16(gB + 96L * 512, dB + 6144);
    gA += 64; gB += 64;
    __syncthreads();
#pragma unroll
    for (int ks = 0; ks < 2; ++ks) {
      short8 af[4], bfr[4];
      const int csl = ((ks * 4 + fq) ^ (fm & 7)) * 8;
#pragma unroll
      for (int x = 0; x < 4; ++x)
        af[x] = *(const short8*)&lA[(wm + x * 16 + fm) * 64 + csl];
#pragma unroll
      for (int y = 0; y < 4; ++y)
        bfr[y] = *(const short8*)&lB[(wn + y * 16 + fm) * 64 + csl];
#pragma unroll
      for (int x = 0; x < 4; ++x)
#pragma unroll
        for (int y = 0; y < 4; ++y)
          acc[x][y] = __builtin_amdgcn_mfma_f32_16x16x32_bf16(af[x], bfr[y], acc[x][y], 0, 0, 0);
    }
    __syncthreads();
  }

  float bs[4];
  int cs[4];
#pragma unroll
  for (int y = 0; y < 4; ++y) {
    bs[y] = bias[n0 + wn + y * 16 + fm] * bsc;
    cs[y] = ((((wn >> 4) + y) ^ fq) * 16) + fm;
  }
#pragma unroll
  for (int x = 0; x < 4; ++x)
#pragma unroll
    for (int r = 0; r < 4; ++r) {
      int rowl = wm + x * 16 + fq * 4 + r;
      unsigned p01 = cvt_pk_bf16(acc[x][0][r] + bs[0], acc[x][1][r] + bs[1]);
      unsigned p23 = cvt_pk_bf16(acc[x][2][r] + bs[2], acc[x][3][r] + bs[3]);
      smem[rowl * 128 + cs[0]] = (u16)p01;
      smem[rowl * 128 + cs[1]] = (u16)(p01 >> 16);
      smem[rowl * 128 + cs[2]] = (u16)p23;
      smem[rowl * 128 + cs[3]] = (u16)(p23 >> 16);
    }
  __syncthreads();
#pragma unroll
  for (int p = 0; p < 8; ++p) {
    int rowl = p * 16 + (t >> 4);
    int c = t & 15;
    int q = (rowl >> 2) & 3;
    short8 v = *(const short8*)&smem[rowl * 128 + (((c >> 1) ^ q) * 16) + (c & 1) * 8];
    *(short8*)(Cout + (long)(m0 + rowl) * 512 + n0 + c * 8) = v;
  }
}

// ------- merged: QK (blocks 0..1023) + v-projT unscaled (1024..1535) --------
// qb is pre-scaled so E = exp2(acc) directly.
__global__ __launch_bounds__(256) void qk_vproj(
    const u16* __restrict__ qb, const u16* __restrict__ kb,
    u16* __restrict__ E, float* __restrict__ Z,
    const u16* __restrict__ wvb, const u16* __restrict__ cb,
    const float* __restrict__ bv, u16* __restrict__ vT,
    float* __restrict__ colV) {
  __shared__ u16 smem[16384];
  __shared__ float colred[128];
  u16* lA = smem;
  u16* lB = smem + 8192;

  const int bx = blockIdx.x;
  const bool is_qk = bx < 1024;
  const u16 *A, *B;
  int m0, n0, b;
  if (is_qk) {
    b = bx & 7;
    n0 = ((bx >> 3) & 15) * 128;
    m0 = (bx >> 7) * 128;
    A = qb + (long)b * (1024L * 512);
    B = kb + (long)b * (2048L * 512);
  } else {
    int e = bx - 1024;
    m0 = (e & 3) * 128;
    n0 = (e >> 2) * 128;
    b = 0;
    A = wvb;
    B = cb;
  }
  const int t = threadIdx.x, wave = t >> 6, lane = t & 63;
  const int fm = lane & 15, fq = lane >> 4;
  const int wm = (wave >> 1) * 64, wn = (wave & 1) * 64;

  const int srow = t >> 3;
  const int swz = ((t & 7) ^ (srow & 7)) * 8;
  const u16* gA = A + (long)(m0 + srow) * 512 + swz;
  const u16* gB = B + (long)(n0 + srow) * 512 + swz;
  u16* dA = lA + wave * 512;
  u16* dB = lB + wave * 512;

  floatx4 acc[4][4];
#pragma unroll
  for (int x = 0; x < 4; ++x)
#pragma unroll
    for (int y = 0; y < 4; ++y) { floatx4 z = {0.f, 0.f, 0.f, 0.f}; acc[x][y] = z; }

#pragma unroll 1
  for (int kt = 0; kt < 8; ++kt) {
    gload16(gA, dA);
    gload16(gA + 32L * 512, dA + 2048);
    gload16(gA + 64L * 512, dA + 4096);
    gload16(gA + 96L * 512, dA + 6144);
    gload16(gB, dB);
    gload16(gB + 32L * 512, dB + 2048);
    gload16(gB + 64L * 512, dB + 4096);
    gload16(gB + 96L * 512, dB + 6144);
    gA += 64; gB += 64;
    __syncthreads();
#pragma unroll
    for (int ks = 0; ks < 2; ++ks) {
      short8 af[4], bfr[4];
      const int csl = ((ks * 4 + fq) ^ (fm & 7)) * 8;
#pragma unroll
      for (int x = 0; x < 4; ++x)
        af[x] = *(const short8*)&lA[(wm + x * 16 + fm) * 64 + csl];
#pragma unroll
      for (int y = 0; y < 4; ++y)
        bfr[y] = *(const short8*)&lB[(wn + y * 16 + fm) * 64 + csl];
#pragma unroll
      for (int x = 0; x < 4; ++x)
#pragma unroll
        for (int y = 0; y < 4; ++y)
          acc[x][y] = __builtin_amdgcn_mfma_f32_16x16x32_bf16(af[x], bfr[y], acc[x][y], 0, 0, 0);
    }
    __syncthreads();
  }

  int cs[4];
#pragma unroll
  for (int y = 0; y < 4; ++y) cs[y] = ((((wn >> 4) + y) ^ fq) * 16) + fm;

  if (is_qk) {
    float s4[4] = {0.f, 0.f, 0.f, 0.f};
#pragma unroll
    for (int x = 0; x < 4; ++x)
#pragma unroll
      for (int r = 0; r < 4; ++r) {
        int rowl = wm + x * 16 + fq * 4 + r;
        float e0 = __builtin_amdgcn_exp2f(acc[x][0][r]);
        float e1 = __builtin_amdgcn_exp2f(acc[x][1][r]);
        float e2 = __builtin_amdgcn_exp2f(acc[x][2][r]);
        float e3 = __builtin_amdgcn_exp2f(acc[x][3][r]);
        s4[0] += e0; s4[1] += e1; s4[2] += e2; s4[3] += e3;
        unsigned p01 = cvt_pk_bf16(e0, e1);
        unsigned p23 = cvt_pk_bf16(e2, e3);
        smem[rowl * 128 + cs[0]] = (u16)p01;
        smem[rowl * 128 + cs[1]] = (u16)(p01 >> 16);
        smem[rowl * 128 + cs[2]] = (u16)p23;
        smem[rowl * 128 + cs[3]] = (u16)(p23 >> 16);
      }
#pragma unroll
    for (int y = 0; y < 4; ++y) {
      s4[y] += __shfl_xor(s4[y], 16, 64);
      s4[y] += __shfl_xor(s4[y], 32, 64);
    }
    if (t < 128) colred[t] = 0.f;
    __syncthreads();
    u16* Eg = E + (long)b * (1024L * 2048);
#pragma unroll
    for (int p = 0; p < 8; ++p) {
      int rowl = p * 16 + (t >> 4);
      int c = t & 15;
      int q = (rowl >> 2) & 3;
      short8 v = *(const short8*)&smem[rowl * 128 + (((c >> 1) ^ q) * 16) + (c & 1) * 8];
      *(short8*)(Eg + (long)(m0 + rowl) * 2048 + n0 + c * 8) = v;
    }
    if (fq == 0) {
#pragma unroll
      for (int y = 0; y < 4; ++y) atomicAdd(&colred[wn + y * 16 + fm], s4[y]);
    }
    __syncthreads();
    if (t < 128) atomicAdd(&Z[b * 2048 + n0 + t], colred[t]);
  } else {
    const int bb = n0 >> 11;
    const int j0c = n0 & 2047;
    float bsr[4][4];
#pragma unroll
    for (int x = 0; x < 4; ++x)
#pragma unroll
      for (int r = 0; r < 4; ++r)
        bsr[x][r] = bv[m0 + wm + x * 16 + fq * 4 + r];
    float rs[4][4];
#pragma unroll
    for (int x = 0; x < 4; ++x)
#pragma unroll
      for (int r = 0; r < 4; ++r) rs[x][r] = 0.f;
#pragma unroll
    for (int x = 0; x < 4; ++x)
#pragma unroll
      for (int r = 0; r < 4; ++r) {
        int rowl = wm + x * 16 + fq * 4 + r;
        float v0 = acc[x][0][r] + bsr[x][r];
        float v1 = acc[x][1][r] + bsr[x][r];
        float v2 = acc[x][2][r] + bsr[x][r];
        float v3 = acc[x][3][r] + bsr[x][r];
        rs[x][r] += v0 + v1 + v2 + v3;
        unsigned p01 = cvt_pk_bf16(v0, v1);
        unsigned p23 = cvt_pk_bf16(v2, v3);
        smem[rowl * 128 + cs[0]] = (u16)p01;
        smem[rowl * 128 + cs[1]] = (u16)(p01 >> 16);
        smem[rowl * 128 + cs[2]] = (u16)p23;
        smem[rowl * 128 + cs[3]] = (u16)(p23 >> 16);
      }
    __syncthreads();
    u16* Cg = vT + (long)bb * (512L * 2048) + j0c;
#pragma unroll
    for (int p = 0; p < 8; ++p) {
      int rowl = p * 16 + (t >> 4);
      int c = t & 15;
      int q = (rowl >> 2) & 3;
      short8 v = *(const short8*)&smem[rowl * 128 + (((c >> 1) ^ q) * 16) + (c & 1) * 8];
      *(short8*)(Cg + (long)(m0 + rowl) * 2048 + c * 8) = v;
    }
#pragma unroll
    for (int x = 0; x < 4; ++x)
#pragma unroll
      for (int r = 0; r < 4; ++r) {
        float s = rs[x][r];
        s += __shfl_xor(s, 1, 64);
        s += __shfl_xor(s, 2, 64);
        s += __shfl_xor(s, 4, 64);
        s += __shfl_xor(s, 8, 64);
        if (fm == 0)
          atomicAdd(&colV[bb * 512 + m0 + wm + x * 16 + fq * 4 + r], s);
      }
  }
}

// ------- PV: out[b][i][d] = (sum_j E[i,j]*vT[d,j]/Z[j] + eps*colV[d])*invR --
// 64x64 tile, BK=64, TWO-barrier schedule (round-7 proven). T14 issue-early:
// V regs for tile kt+1 are loaded BEFORE iteration kt's barrier, so their
// HBM latency is absorbed by the barrier's vmcnt(0) drain -> zero stall at
// the scale point. Memory schedule otherwise identical to round 7.
__global__ __launch_bounds__(256) void gemm_pv(const u16* __restrict__ E,
    const u16* __restrict__ V, const float* __restrict__ colV,
    const float* __restrict__ Z, float* __restrict__ out) {
  __shared__ u16 smem[8192];     // lA | lB in K-loop; 64x64 fp32 tile after
  __shared__ u16 sZb[2048];
  u16* lA = smem;
  u16* lB = smem + 4096;
  const int id = blockIdx.x;
  const int b = id & 7;
  const int m0 = ((id >> 3) & 15) * 64, n0 = (id >> 7) * 64;
  const int t = threadIdx.x, wave = t >> 6, lane = t & 63;
  const int fm = lane & 15, fq = lane >> 4;
  const int wm = (wave >> 1) * 32, wn = (wave & 1) * 32;

  {
    int i = t * 8;
    float4 z0 = *(const float4*)(Z + b * 2048 + i);
    float4 z1 = *(const float4*)(Z + b * 2048 + i + 4);
    union { unsigned u[4]; short8 s8; } o;
    o.u[0] = cvt_pk_bf16(__builtin_amdgcn_rcpf(z0.x), __builtin_amdgcn_rcpf(z0.y));
    o.u[1] = cvt_pk_bf16(__builtin_amdgcn_rcpf(z0.z), __builtin_amdgcn_rcpf(z0.w));
    o.u[2] = cvt_pk_bf16(__builtin_amdgcn_rcpf(z1.x), __builtin_amdgcn_rcpf(z1.y));
    o.u[3] = cvt_pk_bf16(__builtin_amdgcn_rcpf(z1.z), __builtin_amdgcn_rcpf(z1.w));
    *(short8*)&sZb[i] = o.s8;
  }
  __syncthreads();   // loop scale reads sZb

  const int srow = t >> 3;
  const int swz = ((t & 7) ^ (srow & 7)) * 8;
  const u16* gA = E + (long)b * (1024L * 2048) + (long)(m0 + srow) * 2048 + swz;
  const u16* gB = V + (long)b * (512L * 2048) + (long)(n0 + srow) * 2048 + swz;
  u16* dA = lA + wave * 512;
  u16* dB = lB + wave * 512;

  floatx4 acc[2][2];
  floatx4 accR[2];
#pragma unroll
  for (int x = 0; x < 2; ++x) {
    floatx4 z = {0.f, 0.f, 0.f, 0.f};
    accR[x] = z;
#pragma unroll
    for (int y = 0; y < 2; ++y) acc[x][y] = z;
  }

  // V tile 0 -> registers
  short8 rv0 = *(const short8*)gB;
  short8 rv1 = *(const short8*)(gB + 32L * 2048);
  gB += 64;

#pragma unroll 1
  for (int kt = 0; kt < 32; ++kt) {
    // E tile kt -> LDS (async; drains at the barrier)
    gload16(gA, dA);
    gload16(gA + 32L * 2048, dA + 2048);
    gA += 64;
    // scale V tile kt (regs already resident -> no vmem stall here)
    short8 zr = *(const short8*)&sZb[kt * 64 + swz];
    union { unsigned u[4]; short8 s8; } o0, o1;
#pragma unroll
    for (int e = 0; e < 4; ++e) {
      float zlo = bf2f((u16)zr[2 * e]), zhi = bf2f((u16)zr[2 * e + 1]);
      o0.u[e] = cvt_pk_bf16(bf2f((u16)rv0[2 * e]) * zlo,
                            bf2f((u16)rv0[2 * e + 1]) * zhi);
      o1.u[e] = cvt_pk_bf16(bf2f((u16)rv1[2 * e]) * zlo,
                            bf2f((u16)rv1[2 * e + 1]) * zhi);
    }
    u16* db = dB + (lane << 3);
    *(short8*)db = o0.s8;
    *(short8*)(db + 2048) = o1.s8;
    // prefetch V tile kt+1 into regs: latency absorbed by the barrier drain
    if (kt < 31) {
      rv0 = *(const short8*)gB;
      rv1 = *(const short8*)(gB + 32L * 2048);
      gB += 64;
    }
    __syncthreads();
#pragma unroll
    for (int ks = 0; ks < 2; ++ks) {
      short8 af[2], bfr[2];
      const int chunk = ks * 4 + fq;
      const int csl = (chunk ^ (fm & 7)) * 8;
#pragma unroll
      for (int x = 0; x < 2; ++x)
        af[x] = *(const short8*)&lA[(wm + x * 16 + fm) * 64 + csl];
#pragma unroll
      for (int y = 0; y < 2; ++y)
        bfr[y] = *(const short8*)&lB[(wn + y * 16 + fm) * 64 + csl];
      short8 zf = *(const short8*)&sZb[kt * 64 + chunk * 8];
#pragma unroll
      for (int x = 0; x < 2; ++x) {
#pragma unroll
        for (int y = 0; y < 2; ++y)
          acc[x][y] = __builtin_amdgcn_mfma_f32_16x16x32_bf16(af[x], bfr[y], acc[x][y], 0, 0, 0);
        accR[x] = __builtin_amdgcn_mfma_f32_16x16x32_bf16(af[x], zf, accR[x], 0, 0, 0);
      }
    }
    __syncthreads();
  }

  float cv[2];
#pragma unroll
  for (int y = 0; y < 2; ++y) cv[y] = colV[b * 512 + n0 + wn + y * 16 + fm];
  float* sO = (float*)smem;
#pragma unroll
  for (int x = 0; x < 2; ++x)
#pragma unroll
    for (int r = 0; r < 4; ++r) {
      float invR = __builtin_amdgcn_rcpf(accR[x][r] + 2048.f * 1e-8f);
      int rowl = wm + x * 16 + fq * 4 + r;
#pragma unroll
      for (int y = 0; y < 2; ++y) {
        const int cblk = (wn >> 4) + y;
        sO[rowl * 64 + ((cblk ^ fq) * 16) + fm] =
            (acc[x][y][r] + 1e-8f * cv[y]) * invR;
      }
    }
  __syncthreads();
  float* og = out + (long)b * (1024L * 512);
#pragma unroll
  for (int p = 0; p < 4; ++p) {
    int rowl = p * 16 + (t >> 4);
    int c = t & 15;
    int q = (rowl >> 2) & 3;
    float4 v = *(const float4*)&sO[rowl * 64 + (((c >> 2) ^ q) * 16) + (c & 3) * 4];
    *(float4*)(og + (long)(m0 + rowl) * 512 + n0 + c * 4) = v;
  }
}

extern "C" void kernel_launch(void* const* d_in, const int* in_sizes, int n_in,
                              void* d_out, int out_size, void* d_ws, size_t ws_size,
                              hipStream_t stream) {
  const float* inputs  = (const float*)d_in[0];
  const float* context = (const float*)d_in[1];
  const float* ln_in_g = (const float*)d_in[2];
  const float* ln_in_b = (const float*)d_in[3];
  const float* ln_ctx_g = (const float*)d_in[4];
  const float* ln_ctx_b = (const float*)d_in[5];
  const float* Wq = (const float*)d_in[6];
  const float* bq = (const float*)d_in[7];
  const float* Wk = (const float*)d_in[8];
  const float* bk = (const float*)d_in[9];
  const float* Wv = (const float*)d_in[10];
  const float* bv = (const float*)d_in[11];
  float* out = (float*)d_out;

  u16* ws = (u16*)d_ws;
  u16* xb  = ws;                        // [8192][512]
  u16* qb  = xb + 8192L * 512;          // [8192][512]
  u16* cb  = qb + 8192L * 512;          // [16384][512]
  u16* wqb = cb + 16384L * 512;         // [512][512]
  u16* wkb = wqb + 512L * 512;
  u16* wvb = wkb + 512L * 512;
  u16* kb  = wvb + 512L * 512;          // [16384][512]
  u16* vTs = kb + 16384L * 512;         // [8][512][2048] raw (unscaled)
  u16* E   = vTs + 8L * 512 * 2048;     // [8][1024][2048]
  float* Z    = (float*)(E + 8L * 1024 * 2048);   // [8][2048] raw col sums
  float* colV = Z + 8L * 2048;                    // [8][512]

  // 512^-0.5 * log2(e): fold scale AND exp->exp2 factor into Wq/bq
  const float qsc = (float)(0.04419417382415922 * 1.4426950408889634);

  // 1: LN(inputs)+LN(context) wave-per-row + weight cvt + zero Z/colV
  ln_prep<<<6932, 256, 0, stream>>>(inputs, ln_in_g, ln_in_b, xb,
                                    context, ln_ctx_g, ln_ctx_b, cb,
                                    Wq, Wk, Wv, wqb, wkb, wvb, Z, qsc);
  // 2: q-proj (bx<64, bias*qsc) + k-proj (bx>=64)
  gemm_proj<<<dim3(192, 4, 1), 256, 0, stream>>>(xb, wqb, bq, qb,
                                                 cb, wkb, bk, kb, qsc, 1.f);
  // 3: merged QK (E, Z) + v-projT unscaled (vT, colV)
  qk_vproj<<<1536, 256, 0, stream>>>(qb, kb, E, Z, wvb, cb, bv, vTs, colV);
  // 4: PV, 2-barrier schedule, inline R, inline 1/Z V-scaling, T14 issue-early
  gemm_pv<<<1024, 256, 0, stream>>>(E, vTs, colV, Z, out);
}